// Round 6
// baseline (989.506 us; speedup 1.0000x reference)
//
#include <hip/hip_runtime.h>
#include <hip/hip_bf16.h>
#include <cstdint>
#include <cstddef>

#define N_NODES 100000
#define N_EDGES 1600000
#define F_IN    256
#define HID     128
#define SCAN_BLK 1024
#define N_SCAN_BLOCKS ((N_NODES + SCAN_BLK - 1) / SCAN_BLK)   // 98
#define NB       ((N_NODES + 255) >> 8)                        // 391 dst-buckets
#define F3_CHUNK 7168
#define N_CHUNKS ((N_EDGES + F3_CHUNK - 1) / F3_CHUNK)         // 224

typedef __attribute__((ext_vector_type(8))) short  bf16x8;
typedef __attribute__((ext_vector_type(4))) float  f32x4;

static __device__ inline float bf2f(unsigned short u) {
    return __uint_as_float(((unsigned int)u) << 16);
}
static __device__ inline unsigned short f2bf(float f) {
    union { __hip_bfloat16 h; unsigned short u; } c;
    c.h = __float2bfloat16(f);
    return c.u;
}
static __device__ inline float lof(unsigned int w) { return __uint_as_float(w << 16); }
static __device__ inline float hif(unsigned int w) { return __uint_as_float(w & 0xffff0000u); }

// ---------------- utility ----------------

__global__ __launch_bounds__(256) void zero_int_kernel(int* __restrict__ p, int n) {
    int i = blockIdx.x * 256 + threadIdx.x;
    if (i < n) p[i] = 0;
}
__global__ __launch_bounds__(256) void zero_f_kernel(float* __restrict__ p, int n) {
    int i = blockIdx.x * 256 + threadIdx.x;
    if (i < n) p[i] = 0.f;
}

// ---------------- bucketed CSR build ----------------

__global__ __launch_bounds__(256) void bucket_count_kernel(const int* __restrict__ dst,
                                                           int* __restrict__ bcnt, int nE) {
    __shared__ int c[NB];
    for (int i = threadIdx.x; i < NB; i += 256) c[i] = 0;
    __syncthreads();
    int base = blockIdx.x * F3_CHUNK;
    int m = min(F3_CHUNK, nE - base);
    for (int t = threadIdx.x; t < m; t += 256)
        atomicAdd(&c[dst[base + t] >> 8], 1);
    __syncthreads();
    for (int i = threadIdx.x; i < NB; i += 256)
        if (c[i]) atomicAdd(&bcnt[i], c[i]);
}

__global__ __launch_bounds__(512) void scan_bucket_kernel(const int* __restrict__ bcnt,
                                                          int* __restrict__ bbase) {
    __shared__ int s[512];
    int t = threadIdx.x;
    int v = (t < NB) ? bcnt[t] : 0;
    s[t] = v;
    __syncthreads();
    for (int off = 1; off < 512; off <<= 1) {
        int add = (t >= off) ? s[t - off] : 0;
        __syncthreads();
        s[t] += add;
        __syncthreads();
    }
    if (t < NB) bbase[t] = s[t] - v;
    if (t == 0) bbase[NB] = N_EDGES;
}

__global__ __launch_bounds__(256) void stage_kernel(const int* __restrict__ src,
                                                    const int* __restrict__ dst,
                                                    const int* __restrict__ bbase,
                                                    int* __restrict__ gfill,
                                                    int* __restrict__ stg_src,
                                                    int* __restrict__ stg_dst, int nE) {
    __shared__ int ss[F3_CHUNK];
    __shared__ int sd[F3_CHUNK];
    __shared__ int cnt[NB];
    __shared__ int bas[NB];
    int base = blockIdx.x * F3_CHUNK;
    int m = min(F3_CHUNK, nE - base);
    for (int i = threadIdx.x; i < NB; i += 256) cnt[i] = 0;
    __syncthreads();
    for (int t = threadIdx.x; t < m; t += 256) {
        int s = src[base + t];
        int d = dst[base + t];
        ss[t] = s;
        sd[t] = d;
        atomicAdd(&cnt[d >> 8], 1);
    }
    __syncthreads();
    for (int i = threadIdx.x; i < NB; i += 256) {
        int c = cnt[i];
        bas[i] = bbase[i] + (c ? atomicAdd(&gfill[i], c) : 0);
        cnt[i] = 0;
    }
    __syncthreads();
    for (int t = threadIdx.x; t < m; t += 256) {
        int d = sd[t];
        int bkt = d >> 8;
        int k = atomicAdd(&cnt[bkt], 1);
        int pos = bas[bkt] + k;
        stg_src[pos] = ss[t];
        stg_dst[pos] = d;
    }
}

__global__ __launch_bounds__(256) void bucket_deg_kernel(const int* __restrict__ stg_dst,
                                                         const int* __restrict__ bbase,
                                                         int* __restrict__ deg, int n) {
    __shared__ int c[256];
    c[threadIdx.x] = 0;
    __syncthreads();
    int b = blockIdx.x;
    int beg = bbase[b], end = bbase[b + 1];
    for (int t = beg + threadIdx.x; t < end; t += 256)
        atomicAdd(&c[stg_dst[t] & 255], 1);
    __syncthreads();
    int node = b * 256 + threadIdx.x;
    if (node < n) deg[node] = c[threadIdx.x];
}

__global__ __launch_bounds__(256) void bucket_fill_kernel(const int* __restrict__ stg_src,
                                                          const int* __restrict__ stg_dst,
                                                          const int* __restrict__ bbase,
                                                          const int* __restrict__ row_ptr,
                                                          int* __restrict__ csr_src) {
    __shared__ int c[256];
    c[threadIdx.x] = 0;
    __syncthreads();
    int b = blockIdx.x;
    int beg = bbase[b], end = bbase[b + 1];
    for (int t = beg + threadIdx.x; t < end; t += 256) {
        int d = stg_dst[t];
        int k = atomicAdd(&c[d & 255], 1);
        csr_src[row_ptr[d] + k] = stg_src[t];
    }
}

// ---------------- dinv ----------------

__global__ __launch_bounds__(256) void dinv_kernel(const int* __restrict__ deg,
                                                   float* __restrict__ dinv, int n) {
    int i = blockIdx.x * 256 + threadIdx.x;
    if (i < n) dinv[i] = rsqrtf((float)deg[i] + 1.0f);   // +1 self-loop
}

// ---------------- exclusive scan (2-level) over deg -> row_ptr ----------------

__global__ __launch_bounds__(256) void scan_reduce_kernel(const int* __restrict__ deg,
                                                          int n, int* __restrict__ blockSums) {
    __shared__ int red[256];
    int base = blockIdx.x * SCAN_BLK;
    int t = threadIdx.x;
    int s = 0;
#pragma unroll
    for (int k = 0; k < 4; ++k) {
        int idx = base + t * 4 + k;
        if (idx < n) s += deg[idx];
    }
    red[t] = s;
    __syncthreads();
    for (int off = 128; off > 0; off >>= 1) {
        if (t < off) red[t] += red[t + off];
        __syncthreads();
    }
    if (t == 0) blockSums[blockIdx.x] = red[0];
}

__global__ __launch_bounds__(128) void scan_small_kernel(int* __restrict__ data, int n) {
    __shared__ int s[128];
    int t = threadIdx.x;
    int v = (t < n) ? data[t] : 0;
    s[t] = v;
    __syncthreads();
    for (int off = 1; off < 128; off <<= 1) {
        int add = (t >= off) ? s[t - off] : 0;
        __syncthreads();
        s[t] += add;
        __syncthreads();
    }
    if (t < n) data[t] = s[t] - v;   // exclusive
}

__global__ __launch_bounds__(256) void scan_final_kernel(const int* __restrict__ deg, int n,
                                                         const int* __restrict__ blockSums,
                                                         int* __restrict__ row_ptr, int eTotal) {
    __shared__ int pre[256];
    int base = blockIdx.x * SCAN_BLK;
    int t = threadIdx.x;
    int v[4];
    int s = 0;
#pragma unroll
    for (int k = 0; k < 4; ++k) {
        int idx = base + t * 4 + k;
        v[k] = (idx < n) ? deg[idx] : 0;
        s += v[k];
    }
    pre[t] = s;
    __syncthreads();
    for (int off = 1; off < 256; off <<= 1) {
        int add = (t >= off) ? pre[t - off] : 0;
        __syncthreads();
        pre[t] += add;
        __syncthreads();
    }
    int running = blockSums[blockIdx.x] + pre[t] - s;
#pragma unroll
    for (int k = 0; k < 4; ++k) {
        int idx = base + t * 4 + k;
        if (idx < n) row_ptr[idx] = running;
        running += v[k];
    }
    if (blockIdx.x == 0 && t == 0) row_ptr[n] = eTotal;
}

// ---------------- W -> fragment blob (bf16, MFMA B-operand order) -----------

template <int K>
__global__ __launch_bounds__(256) void prep_blob_kernel(const float* __restrict__ W,
                                                        unsigned short* __restrict__ blob) {
    constexpr int TOT = (K / 32) * 8 * 64;
    int tid = blockIdx.x * 256 + threadIdx.x;
    if (tid >= TOT) return;
    int lane = tid & 63;
    int c    = (tid >> 6) & 7;
    int s    = tid >> 9;
    int col  = c * 16 + (lane & 15);
    int kb   = s * 32 + (lane >> 4) * 8;
    bf16x8 o;
#pragma unroll
    for (int j = 0; j < 8; ++j)
        o[j] = (short)f2bf(W[(size_t)(kb + j) * HID + col]);
    *reinterpret_cast<bf16x8*>(blob + (size_t)tid * 8) = o;
}

// ---------------- MFMA GEMM: Y_bf16[N,128] = X[N,K] @ W[K,128] --------------

template <int K, bool IN_BF16>
__global__ __launch_bounds__(256) void mfma_gemm_kernel(const void* __restrict__ Xv,
                                                        const unsigned short* __restrict__ blob,
                                                        unsigned short* __restrict__ Y, int n) {
    constexpr int KSTEPS = K / 32;
    const int lane = threadIdx.x & 63;
    const int wave = threadIdx.x >> 6;
    const int rowbase = blockIdx.x * 128 + wave * 32;

    const int r0 = min(rowbase +      (lane & 15), n - 1);
    const int r1 = min(rowbase + 16 + (lane & 15), n - 1);
    const int koff = (lane >> 4) * 8;

    f32x4 acc0[8], acc1[8];
#pragma unroll
    for (int c = 0; c < 8; ++c) { acc0[c] = (f32x4)0.f; acc1[c] = (f32x4)0.f; }

#pragma unroll
    for (int s = 0; s < KSTEPS; ++s) {
        bf16x8 bfr[8];
#pragma unroll
        for (int c = 0; c < 8; ++c)
            bfr[c] = *reinterpret_cast<const bf16x8*>(blob + ((size_t)((s * 8 + c) * 64 + lane)) * 8);

        bf16x8 a0, a1;
        if (IN_BF16) {
            const unsigned short* Xb = (const unsigned short*)Xv;
            a0 = *reinterpret_cast<const bf16x8*>(Xb + (size_t)r0 * K + s * 32 + koff);
            a1 = *reinterpret_cast<const bf16x8*>(Xb + (size_t)r1 * K + s * 32 + koff);
        } else {
            const float* Xf = (const float*)Xv;
            const float4* p0 = reinterpret_cast<const float4*>(Xf + (size_t)r0 * K + s * 32 + koff);
            const float4* p1 = reinterpret_cast<const float4*>(Xf + (size_t)r1 * K + s * 32 + koff);
            float4 q0 = p0[0], q1 = p0[1], q2 = p1[0], q3 = p1[1];
            a0[0] = (short)f2bf(q0.x); a0[1] = (short)f2bf(q0.y);
            a0[2] = (short)f2bf(q0.z); a0[3] = (short)f2bf(q0.w);
            a0[4] = (short)f2bf(q1.x); a0[5] = (short)f2bf(q1.y);
            a0[6] = (short)f2bf(q1.z); a0[7] = (short)f2bf(q1.w);
            a1[0] = (short)f2bf(q2.x); a1[1] = (short)f2bf(q2.y);
            a1[2] = (short)f2bf(q2.z); a1[3] = (short)f2bf(q2.w);
            a1[4] = (short)f2bf(q3.x); a1[5] = (short)f2bf(q3.y);
            a1[6] = (short)f2bf(q3.z); a1[7] = (short)f2bf(q3.w);
        }

#pragma unroll
        for (int c = 0; c < 8; ++c) {
            acc0[c] = __builtin_amdgcn_mfma_f32_16x16x32_bf16(a0, bfr[c], acc0[c], 0, 0, 0);
            acc1[c] = __builtin_amdgcn_mfma_f32_16x16x32_bf16(a1, bfr[c], acc1[c], 0, 0, 0);
        }
    }

    const int col  = lane & 15;
    const int rsub = (lane >> 4) * 4;
#pragma unroll
    for (int c = 0; c < 8; ++c) {
#pragma unroll
        for (int r = 0; r < 4; ++r) {
            int row0 = rowbase + rsub + r;
            int row1 = rowbase + 16 + rsub + r;
            if (row0 < n) Y[(size_t)row0 * HID + c * 16 + col] = f2bf(acc0[c][r]);
            if (row1 < n) Y[(size_t)row1 * HID + c * 16 + col] = f2bf(acc1[c][r]);
        }
    }
}

// ---------------- aggregation: XCD-affine feature-sliced gather ------------
// slice = blockIdx.x & 7  -> one of 8 column slices (16 cols = 8 u32 words).
// Under round-robin workgroup->XCD dispatch, each XCD's xw working set is
// 100K nodes x 32 B = 3.2 MB < 4 MB L2 -> src gathers become L2 hits.
// Wave: 8 lanes/edge (eg = lane>>3), word wd = lane&7; 8 edges in flight per
// iteration; 3x shfl_xor reduce; 8 nodes serially per wave.

__global__ __launch_bounds__(256) void agg_gather_slice_kernel(
        const unsigned short* __restrict__ xw,
        const float* __restrict__ dinv,
        const int* __restrict__ row_ptr,
        const int* __restrict__ csr_src,
        const float* __restrict__ b,
        unsigned short* __restrict__ h, int n) {
    const int slice = blockIdx.x & 7;
    const int ng    = blockIdx.x >> 3;
    const int wave  = threadIdx.x >> 6;
    const int lane  = threadIdx.x & 63;
    const int eg    = lane >> 3;          // edge subgroup 0..7
    const int wd    = lane & 7;           // u32 word within slice 0..7
    const int colw  = slice * 8 + wd;     // u32 word within row 0..63

    const unsigned int* xw32 = (const unsigned int*)xw;

    const int v0 = (ng * 4 + wave) * 8;   // 8 nodes per wave
#pragma unroll 1
    for (int i = 0; i < 8; ++i) {
        int v = v0 + i;
        if (v >= n) return;
        int beg = __builtin_amdgcn_readfirstlane(row_ptr[v]);
        int end = __builtin_amdgcn_readfirstlane(row_ptr[v + 1]);

        float a0 = 0.f, a1 = 0.f;
        for (int j = beg; j < end; j += 8) {
            int e = j + eg;
            bool p = e < end;
            int s = csr_src[p ? e : (end - 1)];
            float d = p ? dinv[s] : 0.f;
            unsigned int w = xw32[(size_t)s * 64 + colw];
            a0 = fmaf(d, lof(w), a0);
            a1 = fmaf(d, hif(w), a1);
        }
        a0 += __shfl_xor(a0, 8);  a1 += __shfl_xor(a1, 8);
        a0 += __shfl_xor(a0, 16); a1 += __shfl_xor(a1, 16);
        a0 += __shfl_xor(a0, 32); a1 += __shfl_xor(a1, 32);

        if (eg == 0) {
            float dv = dinv[v];
            unsigned int wv = xw32[(size_t)v * 64 + colw];
            float2 bb = *reinterpret_cast<const float2*>(b + 2 * colw);
            float s2v = dv * dv;
            float r0 = fmaxf(dv * a0 + s2v * lof(wv) + bb.x, 0.f);
            float r1 = fmaxf(dv * a1 + s2v * hif(wv) + bb.y, 0.f);
            ushort2 o;
            o.x = f2bf(r0);
            o.y = f2bf(r1);
            *reinterpret_cast<ushort2*>(h + (size_t)v * HID + 2 * colw) = o;
        }
    }
}

// ---------------- classifier + log_softmax ----------------

__global__ __launch_bounds__(256) void classifier_kernel(const unsigned short* __restrict__ h,
                                                         const float* __restrict__ Wc,
                                                         const float* __restrict__ bc,
                                                         float* __restrict__ out, int n) {
    __shared__ float wc0[HID], wc1[HID], bcs[2];
    if (threadIdx.x < HID) {
        wc0[threadIdx.x] = Wc[threadIdx.x * 2 + 0];
        wc1[threadIdx.x] = Wc[threadIdx.x * 2 + 1];
    }
    if (threadIdx.x < 2) bcs[threadIdx.x] = bc[threadIdx.x];
    __syncthreads();

    int i = blockIdx.x * 256 + threadIdx.x;
    if (i >= n) return;
    const ushort4* hr = reinterpret_cast<const ushort4*>(h + (size_t)i * HID);
    float l0 = 0.f, l1 = 0.f;
#pragma unroll
    for (int j4 = 0; j4 < 32; ++j4) {
        ushort4 q = hr[j4];
        float v0 = bf2f(q.x), v1 = bf2f(q.y), v2 = bf2f(q.z), v3 = bf2f(q.w);
        l0 += v0 * wc0[j4 * 4 + 0] + v1 * wc0[j4 * 4 + 1]
            + v2 * wc0[j4 * 4 + 2] + v3 * wc0[j4 * 4 + 3];
        l1 += v0 * wc1[j4 * 4 + 0] + v1 * wc1[j4 * 4 + 1]
            + v2 * wc1[j4 * 4 + 2] + v3 * wc1[j4 * 4 + 3];
    }
    l0 += bcs[0]; l1 += bcs[1];
    float m = fmaxf(l0, l1);
    float lse = m + logf(expf(l0 - m) + expf(l1 - m));
    out[i * 2 + 0] = l0 - lse;
    out[i * 2 + 1] = l1 - lse;
}

// ---------------- launch ----------------

static inline size_t align256(size_t x) { return (x + 255) & ~(size_t)255; }

extern "C" void kernel_launch(void* const* d_in, const int* in_sizes, int n_in,
                              void* d_out, int out_size, void* d_ws, size_t ws_size,
                              hipStream_t stream) {
    const float* x   = (const float*)d_in[0];
    const int*   ei  = (const int*)d_in[1];     // int32 per harness contract
    const float* W1  = (const float*)d_in[2];
    const float* b1  = (const float*)d_in[3];
    const float* W2  = (const float*)d_in[4];
    const float* b2  = (const float*)d_in[5];
    const float* W3  = (const float*)d_in[6];
    const float* b3  = (const float*)d_in[7];
    const float* Wc  = (const float*)d_in[8];
    const float* bc  = (const float*)d_in[9];
    float*       out = (float*)d_out;

    const int* src = ei;             // edge_index[0,:]
    const int* dst = ei + N_EDGES;   // edge_index[1,:]

    // workspace layout
    size_t off = 0;
    size_t o_dinv    = off; off = align256(off + (size_t)N_NODES * 4);
    size_t o_deg     = off; off = align256(off + (size_t)N_NODES * 4);
    size_t o_rowptr  = off; off = align256(off + (size_t)(N_NODES + 1) * 4);
    size_t o_bsums   = off; off = align256(off + (size_t)N_SCAN_BLOCKS * 4);
    size_t o_bcnt    = off; off = align256(off + (size_t)NB * 4);
    size_t o_bbase   = off; off = align256(off + (size_t)(NB + 1) * 4);
    size_t o_gfill   = off; off = align256(off + (size_t)NB * 4);
    size_t o_csr     = off; off = align256(off + (size_t)N_EDGES * 4);
    size_t o_stgs    = off; off = align256(off + (size_t)N_EDGES * 4);
    size_t o_stgd    = off; off = align256(off + (size_t)N_EDGES * 4);
    size_t o_blob1   = off; off = align256(off + (size_t)(F_IN / 32) * 8 * 64 * 8 * 2);
    size_t o_blob2   = off; off = align256(off + (size_t)(HID / 32) * 8 * 64 * 8 * 2);
    size_t o_blob3   = off; off = align256(off + (size_t)(HID / 32) * 8 * 64 * 8 * 2);
    size_t o_bufA    = off; off = align256(off + (size_t)N_NODES * HID * 2);
    size_t o_bufB    = off; off = align256(off + (size_t)N_NODES * HID * 2);
    size_t need = off;                           // ~72 MB

    const int nThr = 256;
    const int gOut = (out_size + nThr - 1) / nThr;
    if (ws_size < need) {
        zero_f_kernel<<<gOut, nThr, 0, stream>>>(out, out_size);
        return;
    }

    char* ws = (char*)d_ws;
    float*          dinv    = (float*)(ws + o_dinv);
    int*            deg     = (int*)(ws + o_deg);
    int*            row_ptr = (int*)(ws + o_rowptr);
    int*            bsums   = (int*)(ws + o_bsums);
    int*            bcnt    = (int*)(ws + o_bcnt);
    int*            bbase   = (int*)(ws + o_bbase);
    int*            gfill   = (int*)(ws + o_gfill);
    int*            csr_src = (int*)(ws + o_csr);
    int*            stg_src = (int*)(ws + o_stgs);
    int*            stg_dst = (int*)(ws + o_stgd);
    unsigned short* blob1   = (unsigned short*)(ws + o_blob1);
    unsigned short* blob2   = (unsigned short*)(ws + o_blob2);
    unsigned short* blob3   = (unsigned short*)(ws + o_blob3);
    unsigned short* bufA    = (unsigned short*)(ws + o_bufA);   // xw (bf16)
    unsigned short* bufB    = (unsigned short*)(ws + o_bufB);   // h  (bf16)

    const int gN = (N_NODES + nThr - 1) / nThr;
    const int gG = (N_NODES + 127) / 128;
    const int gS = 8 * ((N_NODES + 31) / 32);    // sliced gather: 8 slices x 32 nodes/block

    // ---- bucketed CSR build ----
    zero_int_kernel<<<(NB + 255) / 256, nThr, 0, stream>>>(bcnt, NB);
    zero_int_kernel<<<(NB + 255) / 256, nThr, 0, stream>>>(gfill, NB);
    bucket_count_kernel<<<N_CHUNKS, nThr, 0, stream>>>(dst, bcnt, N_EDGES);
    scan_bucket_kernel<<<1, 512, 0, stream>>>(bcnt, bbase);
    stage_kernel<<<N_CHUNKS, nThr, 0, stream>>>(src, dst, bbase, gfill,
                                                stg_src, stg_dst, N_EDGES);
    bucket_deg_kernel<<<NB, nThr, 0, stream>>>(stg_dst, bbase, deg, N_NODES);
    dinv_kernel<<<gN, nThr, 0, stream>>>(deg, dinv, N_NODES);
    scan_reduce_kernel<<<N_SCAN_BLOCKS, nThr, 0, stream>>>(deg, N_NODES, bsums);
    scan_small_kernel<<<1, 128, 0, stream>>>(bsums, N_SCAN_BLOCKS);
    scan_final_kernel<<<N_SCAN_BLOCKS, nThr, 0, stream>>>(deg, N_NODES, bsums, row_ptr, N_EDGES);
    bucket_fill_kernel<<<NB, nThr, 0, stream>>>(stg_src, stg_dst, bbase, row_ptr, csr_src);

    // ---- W blobs ----
    prep_blob_kernel<F_IN><<<16, nThr, 0, stream>>>(W1, blob1);
    prep_blob_kernel<HID><<<8, nThr, 0, stream>>>(W2, blob2);
    prep_blob_kernel<HID><<<8, nThr, 0, stream>>>(W3, blob3);

    // ---- layers ----
    mfma_gemm_kernel<F_IN, false><<<gG, nThr, 0, stream>>>(x, blob1, bufA, N_NODES);
    agg_gather_slice_kernel<<<gS, nThr, 0, stream>>>(bufA, dinv, row_ptr, csr_src, b1, bufB, N_NODES);

    mfma_gemm_kernel<HID, true><<<gG, nThr, 0, stream>>>(bufB, blob2, bufA, N_NODES);
    agg_gather_slice_kernel<<<gS, nThr, 0, stream>>>(bufA, dinv, row_ptr, csr_src, b2, bufB, N_NODES);

    mfma_gemm_kernel<HID, true><<<gG, nThr, 0, stream>>>(bufB, blob3, bufA, N_NODES);
    agg_gather_slice_kernel<<<gS, nThr, 0, stream>>>(bufA, dinv, row_ptr, csr_src, b3, bufB, N_NODES);

    // ---- classifier ----
    classifier_kernel<<<gN, nThr, 0, stream>>>(bufB, Wc, bc, out, N_NODES);
}

// Round 7
// 407.323 us; speedup vs baseline: 2.4293x; 2.4293x over previous
//
#include <hip/hip_runtime.h>
#include <hip/hip_bf16.h>
#include <cstdint>
#include <cstddef>

#define N_NODES 100000
#define N_EDGES 1600000
#define F_IN    256
#define HID     128
#define SCAN_BLK 1024
#define N_SCAN_BLOCKS ((N_NODES + SCAN_BLK - 1) / SCAN_BLK)   // 98
#define NB       ((N_NODES + 255) >> 8)                        // 391 dst-buckets
#define F3_CHUNK 7168
#define N_CHUNKS ((N_EDGES + F3_CHUNK - 1) / F3_CHUNK)         // 224

typedef __attribute__((ext_vector_type(8))) short  bf16x8;
typedef __attribute__((ext_vector_type(4))) float  f32x4;

static __device__ inline float bf2f(unsigned short u) {
    return __uint_as_float(((unsigned int)u) << 16);
}
static __device__ inline unsigned short f2bf(float f) {
    union { __hip_bfloat16 h; unsigned short u; } c;
    c.h = __float2bfloat16(f);
    return c.u;
}
static __device__ inline float lof(unsigned int w) { return __uint_as_float(w << 16); }
static __device__ inline float hif(unsigned int w) { return __uint_as_float(w & 0xffff0000u); }

// ---------------- utility ----------------

__global__ __launch_bounds__(256) void zero_int_kernel(int* __restrict__ p, int n) {
    int i = blockIdx.x * 256 + threadIdx.x;
    if (i < n) p[i] = 0;
}
__global__ __launch_bounds__(256) void zero_f_kernel(float* __restrict__ p, int n) {
    int i = blockIdx.x * 256 + threadIdx.x;
    if (i < n) p[i] = 0.f;
}

// ---------------- bucketed CSR build ----------------

__global__ __launch_bounds__(256) void bucket_count_kernel(const int* __restrict__ dst,
                                                           int* __restrict__ bcnt, int nE) {
    __shared__ int c[NB];
    for (int i = threadIdx.x; i < NB; i += 256) c[i] = 0;
    __syncthreads();
    int base = blockIdx.x * F3_CHUNK;
    int m = min(F3_CHUNK, nE - base);
    for (int t = threadIdx.x; t < m; t += 256)
        atomicAdd(&c[__builtin_nontemporal_load(&dst[base + t]) >> 8], 1);
    __syncthreads();
    for (int i = threadIdx.x; i < NB; i += 256)
        if (c[i]) atomicAdd(&bcnt[i], c[i]);
}

__global__ __launch_bounds__(512) void scan_bucket_kernel(const int* __restrict__ bcnt,
                                                          int* __restrict__ bbase) {
    __shared__ int s[512];
    int t = threadIdx.x;
    int v = (t < NB) ? bcnt[t] : 0;
    s[t] = v;
    __syncthreads();
    for (int off = 1; off < 512; off <<= 1) {
        int add = (t >= off) ? s[t - off] : 0;
        __syncthreads();
        s[t] += add;
        __syncthreads();
    }
    if (t < NB) bbase[t] = s[t] - v;
    if (t == 0) bbase[NB] = N_EDGES;
}

// stage: write packed (src<<8)|(dst&255) grouped by dst-bucket

__global__ __launch_bounds__(256) void stage_kernel(const int* __restrict__ src,
                                                    const int* __restrict__ dst,
                                                    const int* __restrict__ bbase,
                                                    int* __restrict__ gfill,
                                                    unsigned int* __restrict__ stg, int nE) {
    __shared__ int sd[F3_CHUNK];
    __shared__ int cnt[NB];
    __shared__ int bas[NB];
    int base = blockIdx.x * F3_CHUNK;
    int m = min(F3_CHUNK, nE - base);
    for (int i = threadIdx.x; i < NB; i += 256) cnt[i] = 0;
    __syncthreads();
    for (int t = threadIdx.x; t < m; t += 256) {
        int d = __builtin_nontemporal_load(&dst[base + t]);
        sd[t] = d;
        atomicAdd(&cnt[d >> 8], 1);
    }
    __syncthreads();
    for (int i = threadIdx.x; i < NB; i += 256) {
        int c = cnt[i];
        bas[i] = bbase[i] + (c ? atomicAdd(&gfill[i], c) : 0);
        cnt[i] = 0;
    }
    __syncthreads();
    for (int t = threadIdx.x; t < m; t += 256) {
        int d = sd[t];
        int bkt = d >> 8;
        int s = __builtin_nontemporal_load(&src[base + t]);
        int k = atomicAdd(&cnt[bkt], 1);
        __builtin_nontemporal_store(((unsigned int)s << 8) | (unsigned int)(d & 255),
                                    &stg[bas[bkt] + k]);
    }
}

__global__ __launch_bounds__(256) void bucket_deg_kernel(const unsigned int* __restrict__ stg,
                                                         const int* __restrict__ bbase,
                                                         int* __restrict__ deg, int n) {
    __shared__ int c[256];
    c[threadIdx.x] = 0;
    __syncthreads();
    int b = blockIdx.x;
    int beg = bbase[b], end = bbase[b + 1];
    for (int t = beg + threadIdx.x; t < end; t += 256)
        atomicAdd(&c[__builtin_nontemporal_load(&stg[t]) & 255u], 1);
    __syncthreads();
    int node = b * 256 + threadIdx.x;
    if (node < n) deg[node] = c[threadIdx.x];
}

__global__ __launch_bounds__(256) void bucket_fill_kernel(const unsigned int* __restrict__ stg,
                                                          const int* __restrict__ bbase,
                                                          const int* __restrict__ row_ptr,
                                                          int* __restrict__ csr_src) {
    __shared__ int c[256];
    c[threadIdx.x] = 0;
    __syncthreads();
    int b = blockIdx.x;
    int beg = bbase[b], end = bbase[b + 1];
    for (int t = beg + threadIdx.x; t < end; t += 256) {
        unsigned int p = __builtin_nontemporal_load(&stg[t]);
        int dl = (int)(p & 255u);
        int s  = (int)(p >> 8);
        int k = atomicAdd(&c[dl], 1);
        int d = b * 256 + dl;
        csr_src[row_ptr[d] + k] = s;
    }
}

// ---------------- dinv ----------------

__global__ __launch_bounds__(256) void dinv_kernel(const int* __restrict__ deg,
                                                   float* __restrict__ dinv, int n) {
    int i = blockIdx.x * 256 + threadIdx.x;
    if (i < n) dinv[i] = rsqrtf((float)deg[i] + 1.0f);   // +1 self-loop
}

// ---------------- exclusive scan (2-level) over deg -> row_ptr ----------------

__global__ __launch_bounds__(256) void scan_reduce_kernel(const int* __restrict__ deg,
                                                          int n, int* __restrict__ blockSums) {
    __shared__ int red[256];
    int base = blockIdx.x * SCAN_BLK;
    int t = threadIdx.x;
    int s = 0;
#pragma unroll
    for (int k = 0; k < 4; ++k) {
        int idx = base + t * 4 + k;
        if (idx < n) s += deg[idx];
    }
    red[t] = s;
    __syncthreads();
    for (int off = 128; off > 0; off >>= 1) {
        if (t < off) red[t] += red[t + off];
        __syncthreads();
    }
    if (t == 0) blockSums[blockIdx.x] = red[0];
}

__global__ __launch_bounds__(128) void scan_small_kernel(int* __restrict__ data, int n) {
    __shared__ int s[128];
    int t = threadIdx.x;
    int v = (t < n) ? data[t] : 0;
    s[t] = v;
    __syncthreads();
    for (int off = 1; off < 128; off <<= 1) {
        int add = (t >= off) ? s[t - off] : 0;
        __syncthreads();
        s[t] += add;
        __syncthreads();
    }
    if (t < n) data[t] = s[t] - v;   // exclusive
}

__global__ __launch_bounds__(256) void scan_final_kernel(const int* __restrict__ deg, int n,
                                                         const int* __restrict__ blockSums,
                                                         int* __restrict__ row_ptr, int eTotal) {
    __shared__ int pre[256];
    int base = blockIdx.x * SCAN_BLK;
    int t = threadIdx.x;
    int v[4];
    int s = 0;
#pragma unroll
    for (int k = 0; k < 4; ++k) {
        int idx = base + t * 4 + k;
        v[k] = (idx < n) ? deg[idx] : 0;
        s += v[k];
    }
    pre[t] = s;
    __syncthreads();
    for (int off = 1; off < 256; off <<= 1) {
        int add = (t >= off) ? pre[t - off] : 0;
        __syncthreads();
        pre[t] += add;
        __syncthreads();
    }
    int running = blockSums[blockIdx.x] + pre[t] - s;
#pragma unroll
    for (int k = 0; k < 4; ++k) {
        int idx = base + t * 4 + k;
        if (idx < n) row_ptr[idx] = running;
        running += v[k];
    }
    if (blockIdx.x == 0 && t == 0) row_ptr[n] = eTotal;
}

// ---------------- W -> fragment blob (bf16, MFMA B-operand order) -----------

template <int K>
__global__ __launch_bounds__(256) void prep_blob_kernel(const float* __restrict__ W,
                                                        unsigned short* __restrict__ blob) {
    constexpr int TOT = (K / 32) * 8 * 64;
    int tid = blockIdx.x * 256 + threadIdx.x;
    if (tid >= TOT) return;
    int lane = tid & 63;
    int c    = (tid >> 6) & 7;
    int s    = tid >> 9;
    int col  = c * 16 + (lane & 15);
    int kb   = s * 32 + (lane >> 4) * 8;
    bf16x8 o;
#pragma unroll
    for (int j = 0; j < 8; ++j)
        o[j] = (short)f2bf(W[(size_t)(kb + j) * HID + col]);
    *reinterpret_cast<bf16x8*>(blob + (size_t)tid * 8) = o;
}

// ---------------- MFMA GEMM: Y_bf16[N,128] = X[N,K] @ W[K,128] --------------

template <int K, bool IN_BF16>
__global__ __launch_bounds__(256) void mfma_gemm_kernel(const void* __restrict__ Xv,
                                                        const unsigned short* __restrict__ blob,
                                                        unsigned short* __restrict__ Y, int n) {
    constexpr int KSTEPS = K / 32;
    const int lane = threadIdx.x & 63;
    const int wave = threadIdx.x >> 6;
    const int rowbase = blockIdx.x * 128 + wave * 32;

    const int r0 = min(rowbase +      (lane & 15), n - 1);
    const int r1 = min(rowbase + 16 + (lane & 15), n - 1);
    const int koff = (lane >> 4) * 8;

    f32x4 acc0[8], acc1[8];
#pragma unroll
    for (int c = 0; c < 8; ++c) { acc0[c] = (f32x4)0.f; acc1[c] = (f32x4)0.f; }

#pragma unroll
    for (int s = 0; s < KSTEPS; ++s) {
        bf16x8 bfr[8];
#pragma unroll
        for (int c = 0; c < 8; ++c)
            bfr[c] = *reinterpret_cast<const bf16x8*>(blob + ((size_t)((s * 8 + c) * 64 + lane)) * 8);

        bf16x8 a0, a1;
        if (IN_BF16) {
            const unsigned short* Xb = (const unsigned short*)Xv;
            a0 = *reinterpret_cast<const bf16x8*>(Xb + (size_t)r0 * K + s * 32 + koff);
            a1 = *reinterpret_cast<const bf16x8*>(Xb + (size_t)r1 * K + s * 32 + koff);
        } else {
            const float* Xf = (const float*)Xv;
            const float4* p0 = reinterpret_cast<const float4*>(Xf + (size_t)r0 * K + s * 32 + koff);
            const float4* p1 = reinterpret_cast<const float4*>(Xf + (size_t)r1 * K + s * 32 + koff);
            float4 q0 = p0[0], q1 = p0[1], q2 = p1[0], q3 = p1[1];
            a0[0] = (short)f2bf(q0.x); a0[1] = (short)f2bf(q0.y);
            a0[2] = (short)f2bf(q0.z); a0[3] = (short)f2bf(q0.w);
            a0[4] = (short)f2bf(q1.x); a0[5] = (short)f2bf(q1.y);
            a0[6] = (short)f2bf(q1.z); a0[7] = (short)f2bf(q1.w);
            a1[0] = (short)f2bf(q2.x); a1[1] = (short)f2bf(q2.y);
            a1[2] = (short)f2bf(q2.z); a1[3] = (short)f2bf(q2.w);
            a1[4] = (short)f2bf(q3.x); a1[5] = (short)f2bf(q3.y);
            a1[6] = (short)f2bf(q3.z); a1[7] = (short)f2bf(q3.w);
        }

#pragma unroll
        for (int c = 0; c < 8; ++c) {
            acc0[c] = __builtin_amdgcn_mfma_f32_16x16x32_bf16(a0, bfr[c], acc0[c], 0, 0, 0);
            acc1[c] = __builtin_amdgcn_mfma_f32_16x16x32_bf16(a1, bfr[c], acc1[c], 0, 0, 0);
        }
    }

    const int col  = lane & 15;
    const int rsub = (lane >> 4) * 4;
#pragma unroll
    for (int c = 0; c < 8; ++c) {
#pragma unroll
        for (int r = 0; r < 4; ++r) {
            int row0 = rowbase + rsub + r;
            int row1 = rowbase + 16 + rsub + r;
            if (row0 < n) Y[(size_t)row0 * HID + c * 16 + col] = f2bf(acc0[c][r]);
            if (row1 < n) Y[(size_t)row1 * HID + c * 16 + col] = f2bf(acc1[c][r]);
        }
    }
}

// ---------------- aggregation (gather, one wave per node, scalarized) -------
// h[v] = relu( dinv[v]*sum_s dinv[s]*xw[s] + dinv[v]^2*xw[v] + b )
// CLS: fuse final classifier + log_softmax instead of writing h.

template <bool CLS>
__global__ __launch_bounds__(256) void agg_gather_kernel(const unsigned short* __restrict__ xw,
                                                         const float* __restrict__ dinv,
                                                         const int* __restrict__ row_ptr,
                                                         const int* __restrict__ csr_src,
                                                         const float* __restrict__ b,
                                                         unsigned short* __restrict__ h,
                                                         const float* __restrict__ Wc,
                                                         const float* __restrict__ bc,
                                                         float* __restrict__ out, int n) {
    int v = (blockIdx.x * 256 + threadIdx.x) >> 6;
    if (v >= n) return;
    int lane = threadIdx.x & 63;

    int beg = __builtin_amdgcn_readfirstlane(__builtin_nontemporal_load(&row_ptr[v]));
    int end = __builtin_amdgcn_readfirstlane(__builtin_nontemporal_load(&row_ptr[v + 1]));

    const unsigned int* xw32 = (const unsigned int*)xw;   // 2 bf16 per word
    float a0 = 0.f, a1 = 0.f;                              // cols 2*lane, 2*lane+1

    int j = beg;
    for (; j + 4 <= end; j += 4) {
        int s0 = __builtin_amdgcn_readfirstlane(__builtin_nontemporal_load(&csr_src[j + 0]));
        int s1 = __builtin_amdgcn_readfirstlane(__builtin_nontemporal_load(&csr_src[j + 1]));
        int s2 = __builtin_amdgcn_readfirstlane(__builtin_nontemporal_load(&csr_src[j + 2]));
        int s3 = __builtin_amdgcn_readfirstlane(__builtin_nontemporal_load(&csr_src[j + 3]));
        float d0 = dinv[s0], d1 = dinv[s1], d2 = dinv[s2], d3 = dinv[s3];
        unsigned int w0 = xw32[(size_t)s0 * 64 + lane];
        unsigned int w1 = xw32[(size_t)s1 * 64 + lane];
        unsigned int w2 = xw32[(size_t)s2 * 64 + lane];
        unsigned int w3 = xw32[(size_t)s3 * 64 + lane];
        a0 = fmaf(d0, lof(w0), a0); a1 = fmaf(d0, hif(w0), a1);
        a0 = fmaf(d1, lof(w1), a0); a1 = fmaf(d1, hif(w1), a1);
        a0 = fmaf(d2, lof(w2), a0); a1 = fmaf(d2, hif(w2), a1);
        a0 = fmaf(d3, lof(w3), a0); a1 = fmaf(d3, hif(w3), a1);
    }
    for (; j < end; ++j) {
        int s0 = __builtin_amdgcn_readfirstlane(__builtin_nontemporal_load(&csr_src[j]));
        float d0 = dinv[s0];
        unsigned int w0 = xw32[(size_t)s0 * 64 + lane];
        a0 = fmaf(d0, lof(w0), a0); a1 = fmaf(d0, hif(w0), a1);
    }

    float dv = dinv[v];
    unsigned int wv = xw32[(size_t)v * 64 + lane];
    float2 bb = *reinterpret_cast<const float2*>(b + 2 * lane);
    float s2v = dv * dv;
    float r0 = fmaxf(dv * a0 + s2v * lof(wv) + bb.x, 0.f);
    float r1 = fmaxf(dv * a1 + s2v * hif(wv) + bb.y, 0.f);

    if (!CLS) {
        unsigned int o = (unsigned int)f2bf(r0) | ((unsigned int)f2bf(r1) << 16);
        __builtin_nontemporal_store(o,
            reinterpret_cast<unsigned int*>(h + (size_t)v * HID + 2 * lane));
    } else {
        // Wc[c*2+0]=class0 col c, [c*2+1]=class1. float4 at index lane covers cols 2l,2l+1.
        float4 qw = *reinterpret_cast<const float4*>(Wc + 4 * lane);
        float p0 = r0 * qw.x + r1 * qw.z;
        float p1 = r0 * qw.y + r1 * qw.w;
#pragma unroll
        for (int off = 1; off < 64; off <<= 1) {
            p0 += __shfl_xor(p0, off);
            p1 += __shfl_xor(p1, off);
        }
        if (lane == 0) {
            float l0 = p0 + bc[0];
            float l1 = p1 + bc[1];
            float m = fmaxf(l0, l1);
            float lse = m + logf(expf(l0 - m) + expf(l1 - m));
            out[(size_t)v * 2 + 0] = l0 - lse;
            out[(size_t)v * 2 + 1] = l1 - lse;
        }
    }
}

// ---------------- launch ----------------

static inline size_t align256(size_t x) { return (x + 255) & ~(size_t)255; }

extern "C" void kernel_launch(void* const* d_in, const int* in_sizes, int n_in,
                              void* d_out, int out_size, void* d_ws, size_t ws_size,
                              hipStream_t stream) {
    const float* x   = (const float*)d_in[0];
    const int*   ei  = (const int*)d_in[1];     // int32 per harness contract
    const float* W1  = (const float*)d_in[2];
    const float* b1  = (const float*)d_in[3];
    const float* W2  = (const float*)d_in[4];
    const float* b2  = (const float*)d_in[5];
    const float* W3  = (const float*)d_in[6];
    const float* b3  = (const float*)d_in[7];
    const float* Wc  = (const float*)d_in[8];
    const float* bc  = (const float*)d_in[9];
    float*       out = (float*)d_out;

    const int* src = ei;             // edge_index[0,:]
    const int* dst = ei + N_EDGES;   // edge_index[1,:]

    // workspace layout (bcnt and gfill intentionally adjacent for one zero pass)
    size_t off = 0;
    size_t o_dinv    = off; off = align256(off + (size_t)N_NODES * 4);
    size_t o_deg     = off; off = align256(off + (size_t)N_NODES * 4);
    size_t o_rowptr  = off; off = align256(off + (size_t)(N_NODES + 1) * 4);
    size_t o_bsums   = off; off = align256(off + (size_t)N_SCAN_BLOCKS * 4);
    size_t o_bcnt    = off;
    size_t o_gfill   = o_bcnt + (size_t)NB * 4;
                            off = align256(o_gfill + (size_t)NB * 4);
    size_t o_bbase   = off; off = align256(off + (size_t)(NB + 1) * 4);
    size_t o_csr     = off; off = align256(off + (size_t)N_EDGES * 4);
    size_t o_stg     = off; off = align256(off + (size_t)N_EDGES * 4);
    size_t o_blob1   = off; off = align256(off + (size_t)(F_IN / 32) * 8 * 64 * 8 * 2);
    size_t o_blob2   = off; off = align256(off + (size_t)(HID / 32) * 8 * 64 * 8 * 2);
    size_t o_blob3   = off; off = align256(off + (size_t)(HID / 32) * 8 * 64 * 8 * 2);
    size_t o_bufA    = off; off = align256(off + (size_t)N_NODES * HID * 2);
    size_t o_bufB    = off; off = align256(off + (size_t)N_NODES * HID * 2);
    size_t need = off;                           // ~65 MB

    const int nThr = 256;
    const int gOut = (out_size + nThr - 1) / nThr;
    if (ws_size < need) {
        zero_f_kernel<<<gOut, nThr, 0, stream>>>(out, out_size);
        return;
    }

    char* ws = (char*)d_ws;
    float*          dinv    = (float*)(ws + o_dinv);
    int*            deg     = (int*)(ws + o_deg);
    int*            row_ptr = (int*)(ws + o_rowptr);
    int*            bsums   = (int*)(ws + o_bsums);
    int*            bcnt    = (int*)(ws + o_bcnt);
    int*            gfill   = (int*)(ws + o_gfill);
    int*            bbase   = (int*)(ws + o_bbase);
    int*            csr_src = (int*)(ws + o_csr);
    unsigned int*   stg     = (unsigned int*)(ws + o_stg);
    unsigned short* blob1   = (unsigned short*)(ws + o_blob1);
    unsigned short* blob2   = (unsigned short*)(ws + o_blob2);
    unsigned short* blob3   = (unsigned short*)(ws + o_blob3);
    unsigned short* bufA    = (unsigned short*)(ws + o_bufA);   // xw (bf16)
    unsigned short* bufB    = (unsigned short*)(ws + o_bufB);   // h  (bf16)

    const int gN = (N_NODES + nThr - 1) / nThr;
    const int gW = (N_NODES * 64 + nThr - 1) / nThr;   // one wave per node
    const int gG = (N_NODES + 127) / 128;

    // ---- bucketed CSR build ----
    zero_int_kernel<<<(2 * NB + 255) / 256, nThr, 0, stream>>>(bcnt, 2 * NB); // bcnt+gfill
    bucket_count_kernel<<<N_CHUNKS, nThr, 0, stream>>>(dst, bcnt, N_EDGES);
    scan_bucket_kernel<<<1, 512, 0, stream>>>(bcnt, bbase);
    stage_kernel<<<N_CHUNKS, nThr, 0, stream>>>(src, dst, bbase, gfill, stg, N_EDGES);
    bucket_deg_kernel<<<NB, nThr, 0, stream>>>(stg, bbase, deg, N_NODES);
    dinv_kernel<<<gN, nThr, 0, stream>>>(deg, dinv, N_NODES);
    scan_reduce_kernel<<<N_SCAN_BLOCKS, nThr, 0, stream>>>(deg, N_NODES, bsums);
    scan_small_kernel<<<1, 128, 0, stream>>>(bsums, N_SCAN_BLOCKS);
    scan_final_kernel<<<N_SCAN_BLOCKS, nThr, 0, stream>>>(deg, N_NODES, bsums, row_ptr, N_EDGES);
    bucket_fill_kernel<<<NB, nThr, 0, stream>>>(stg, bbase, row_ptr, csr_src);

    // ---- W blobs ----
    prep_blob_kernel<F_IN><<<16, nThr, 0, stream>>>(W1, blob1);
    prep_blob_kernel<HID><<<8, nThr, 0, stream>>>(W2, blob2);
    prep_blob_kernel<HID><<<8, nThr, 0, stream>>>(W3, blob3);

    // ---- layers ----
    mfma_gemm_kernel<F_IN, false><<<gG, nThr, 0, stream>>>(x, blob1, bufA, N_NODES);
    agg_gather_kernel<false><<<gW, nThr, 0, stream>>>(bufA, dinv, row_ptr, csr_src, b1,
                                                      bufB, nullptr, nullptr, nullptr, N_NODES);

    mfma_gemm_kernel<HID, true><<<gG, nThr, 0, stream>>>(bufB, blob2, bufA, N_NODES);
    agg_gather_kernel<false><<<gW, nThr, 0, stream>>>(bufA, dinv, row_ptr, csr_src, b2,
                                                      bufB, nullptr, nullptr, nullptr, N_NODES);

    mfma_gemm_kernel<HID, true><<<gG, nThr, 0, stream>>>(bufB, blob3, bufA, N_NODES);
    // layer-3 aggregation with fused classifier + log_softmax
    agg_gather_kernel<true><<<gW, nThr, 0, stream>>>(bufA, dinv, row_ptr, csr_src, b3,
                                                     nullptr, Wc, bc, out, N_NODES);
}

// Round 8
// 336.629 us; speedup vs baseline: 2.9395x; 1.2100x over previous
//
#include <hip/hip_runtime.h>
#include <hip/hip_bf16.h>
#include <cstdint>
#include <cstddef>

#define N_NODES 100000
#define N_EDGES 1600000
#define F_IN    256
#define HID     128
#define NB       ((N_NODES + 255) >> 8)                        // 391 dst-buckets
#define F3_CHUNK 7168
#define N_CHUNKS ((N_EDGES + F3_CHUNK - 1) / F3_CHUNK)         // 224

typedef __attribute__((ext_vector_type(8))) short  bf16x8;
typedef __attribute__((ext_vector_type(4))) float  f32x4;

static __device__ inline float bf2f(unsigned short u) {
    return __uint_as_float(((unsigned int)u) << 16);
}
static __device__ inline unsigned short f2bf(float f) {
    union { __hip_bfloat16 h; unsigned short u; } c;
    c.h = __float2bfloat16(f);
    return c.u;
}
static __device__ inline float lof(unsigned int w) { return __uint_as_float(w << 16); }
static __device__ inline float hif(unsigned int w) { return __uint_as_float(w & 0xffff0000u); }

// ---------------- utility ----------------

__global__ __launch_bounds__(256) void zero_int_kernel(int* __restrict__ p, int n) {
    int i = blockIdx.x * 256 + threadIdx.x;
    if (i < n) p[i] = 0;
}
__global__ __launch_bounds__(256) void zero_f_kernel(float* __restrict__ p, int n) {
    int i = blockIdx.x * 256 + threadIdx.x;
    if (i < n) p[i] = 0.f;
}

// ---------------- bucketed CSR build ----------------

__global__ __launch_bounds__(256) void bucket_count_kernel(const int* __restrict__ dst,
                                                           int* __restrict__ bcnt, int nE) {
    __shared__ int c[NB];
    for (int i = threadIdx.x; i < NB; i += 256) c[i] = 0;
    __syncthreads();
    int base = blockIdx.x * F3_CHUNK;
    int m = min(F3_CHUNK, nE - base);
    for (int t = threadIdx.x; t < m; t += 256)
        atomicAdd(&c[dst[base + t] >> 8], 1);
    __syncthreads();
    for (int i = threadIdx.x; i < NB; i += 256)
        if (c[i]) atomicAdd(&bcnt[i], c[i]);
}

__global__ __launch_bounds__(512) void scan_bucket_kernel(const int* __restrict__ bcnt,
                                                          int* __restrict__ bbase) {
    __shared__ int s[512];
    int t = threadIdx.x;
    int v = (t < NB) ? bcnt[t] : 0;
    s[t] = v;
    __syncthreads();
    for (int off = 1; off < 512; off <<= 1) {
        int add = (t >= off) ? s[t - off] : 0;
        __syncthreads();
        s[t] += add;
        __syncthreads();
    }
    if (t < NB) bbase[t] = s[t] - v;
    if (t == 0) bbase[NB] = N_EDGES;
}

// stage: write packed (src<<8)|(dst&255) grouped by dst-bucket

__global__ __launch_bounds__(256) void stage_kernel(const int* __restrict__ src,
                                                    const int* __restrict__ dst,
                                                    const int* __restrict__ bbase,
                                                    int* __restrict__ gfill,
                                                    unsigned int* __restrict__ stg, int nE) {
    __shared__ int sd[F3_CHUNK];
    __shared__ int cnt[NB];
    __shared__ int bas[NB];
    int base = blockIdx.x * F3_CHUNK;
    int m = min(F3_CHUNK, nE - base);
    for (int i = threadIdx.x; i < NB; i += 256) cnt[i] = 0;
    __syncthreads();
    for (int t = threadIdx.x; t < m; t += 256) {
        int d = dst[base + t];
        sd[t] = d;
        atomicAdd(&cnt[d >> 8], 1);
    }
    __syncthreads();
    for (int i = threadIdx.x; i < NB; i += 256) {
        int c = cnt[i];
        bas[i] = bbase[i] + (c ? atomicAdd(&gfill[i], c) : 0);
        cnt[i] = 0;
    }
    __syncthreads();
    for (int t = threadIdx.x; t < m; t += 256) {
        int d = sd[t];
        int bkt = d >> 8;
        int s = src[base + t];
        int k = atomicAdd(&cnt[bkt], 1);
        stg[bas[bkt] + k] = ((unsigned int)s << 8) | (unsigned int)(d & 255);
    }
}

// fused finalize: per-bucket deg -> dinv, LDS scan -> row_ptr, fill -> csr_src
// Replaces bucket_deg + dinv + 3-stage global scan + bucket_fill.
// row_ptr[node] = bbase[b] + local_exclusive_scan(local deg).

__global__ __launch_bounds__(256) void bucket_finalize_kernel(
        const unsigned int* __restrict__ stg,
        const int* __restrict__ bbase,
        float* __restrict__ dinv,
        int* __restrict__ row_ptr,
        int* __restrict__ csr_src, int n) {
    __shared__ int c[256];
    __shared__ int s[256];
    __shared__ int lofs[256];
    const int b = blockIdx.x;
    const int t = threadIdx.x;
    const int beg = bbase[b], end = bbase[b + 1];

    c[t] = 0;
    __syncthreads();
    for (int i = beg + t; i < end; i += 256)
        atomicAdd(&c[stg[i] & 255u], 1);
    __syncthreads();

    const int node = b * 256 + t;
    const int myDeg = c[t];
    if (node < n) dinv[node] = rsqrtf((float)myDeg + 1.0f);   // +1 self-loop

    // inclusive Hillis-Steele scan of degs
    s[t] = myDeg;
    __syncthreads();
    for (int off = 1; off < 256; off <<= 1) {
        int add = (t >= off) ? s[t - off] : 0;
        __syncthreads();
        s[t] += add;
        __syncthreads();
    }
    const int excl = s[t] - myDeg;
    lofs[t] = excl;
    if (node <= n) row_ptr[node] = beg + excl;   // node==n lands on end-of-array

    // fill pass (reuse c as running counters)
    __syncthreads();
    c[t] = 0;
    __syncthreads();
    for (int i = beg + t; i < end; i += 256) {
        unsigned int p = stg[i];
        int dl = (int)(p & 255u);
        int k = atomicAdd(&c[dl], 1);
        csr_src[beg + lofs[dl] + k] = (int)(p >> 8);
    }
}

// ---------------- W -> fragment blob (bf16, MFMA B-operand order) -----------

template <int K>
__global__ __launch_bounds__(256) void prep_blob_kernel(const float* __restrict__ W,
                                                        unsigned short* __restrict__ blob) {
    constexpr int TOT = (K / 32) * 8 * 64;
    int tid = blockIdx.x * 256 + threadIdx.x;
    if (tid >= TOT) return;
    int lane = tid & 63;
    int c    = (tid >> 6) & 7;
    int s    = tid >> 9;
    int col  = c * 16 + (lane & 15);
    int kb   = s * 32 + (lane >> 4) * 8;
    bf16x8 o;
#pragma unroll
    for (int j = 0; j < 8; ++j)
        o[j] = (short)f2bf(W[(size_t)(kb + j) * HID + col]);
    *reinterpret_cast<bf16x8*>(blob + (size_t)tid * 8) = o;
}

// ---------------- MFMA GEMM: Y_bf16[N,128] = X[N,K] @ W[K,128] --------------

template <int K, bool IN_BF16>
__global__ __launch_bounds__(256) void mfma_gemm_kernel(const void* __restrict__ Xv,
                                                        const unsigned short* __restrict__ blob,
                                                        unsigned short* __restrict__ Y, int n) {
    constexpr int KSTEPS = K / 32;
    const int lane = threadIdx.x & 63;
    const int wave = threadIdx.x >> 6;
    const int rowbase = blockIdx.x * 128 + wave * 32;

    const int r0 = min(rowbase +      (lane & 15), n - 1);
    const int r1 = min(rowbase + 16 + (lane & 15), n - 1);
    const int koff = (lane >> 4) * 8;

    f32x4 acc0[8], acc1[8];
#pragma unroll
    for (int c = 0; c < 8; ++c) { acc0[c] = (f32x4)0.f; acc1[c] = (f32x4)0.f; }

#pragma unroll
    for (int s = 0; s < KSTEPS; ++s) {
        bf16x8 bfr[8];
#pragma unroll
        for (int c = 0; c < 8; ++c)
            bfr[c] = *reinterpret_cast<const bf16x8*>(blob + ((size_t)((s * 8 + c) * 64 + lane)) * 8);

        bf16x8 a0, a1;
        if (IN_BF16) {
            const unsigned short* Xb = (const unsigned short*)Xv;
            a0 = *reinterpret_cast<const bf16x8*>(Xb + (size_t)r0 * K + s * 32 + koff);
            a1 = *reinterpret_cast<const bf16x8*>(Xb + (size_t)r1 * K + s * 32 + koff);
        } else {
            const float* Xf = (const float*)Xv;
            const float4* p0 = reinterpret_cast<const float4*>(Xf + (size_t)r0 * K + s * 32 + koff);
            const float4* p1 = reinterpret_cast<const float4*>(Xf + (size_t)r1 * K + s * 32 + koff);
            float4 q0 = p0[0], q1 = p0[1], q2 = p1[0], q3 = p1[1];
            a0[0] = (short)f2bf(q0.x); a0[1] = (short)f2bf(q0.y);
            a0[2] = (short)f2bf(q0.z); a0[3] = (short)f2bf(q0.w);
            a0[4] = (short)f2bf(q1.x); a0[5] = (short)f2bf(q1.y);
            a0[6] = (short)f2bf(q1.z); a0[7] = (short)f2bf(q1.w);
            a1[0] = (short)f2bf(q2.x); a1[1] = (short)f2bf(q2.y);
            a1[2] = (short)f2bf(q2.z); a1[3] = (short)f2bf(q2.w);
            a1[4] = (short)f2bf(q3.x); a1[5] = (short)f2bf(q3.y);
            a1[6] = (short)f2bf(q3.z); a1[7] = (short)f2bf(q3.w);
        }

#pragma unroll
        for (int c = 0; c < 8; ++c) {
            acc0[c] = __builtin_amdgcn_mfma_f32_16x16x32_bf16(a0, bfr[c], acc0[c], 0, 0, 0);
            acc1[c] = __builtin_amdgcn_mfma_f32_16x16x32_bf16(a1, bfr[c], acc1[c], 0, 0, 0);
        }
    }

    const int col  = lane & 15;
    const int rsub = (lane >> 4) * 4;
#pragma unroll
    for (int c = 0; c < 8; ++c) {
#pragma unroll
        for (int r = 0; r < 4; ++r) {
            int row0 = rowbase + rsub + r;
            int row1 = rowbase + 16 + rsub + r;
            if (row0 < n) Y[(size_t)row0 * HID + c * 16 + col] = f2bf(acc0[c][r]);
            if (row1 < n) Y[(size_t)row1 * HID + c * 16 + col] = f2bf(acc1[c][r]);
        }
    }
}

// ---------------- aggregation (gather, one wave per node, scalarized) -------
// h[v] = relu( dinv[v]*sum_s dinv[s]*xw[s] + dinv[v]^2*xw[v] + b )
// Plain loads (uniform addrs -> SALU s_loads). CLS fuses classifier+logsoftmax.

template <bool CLS>
__global__ __launch_bounds__(256) void agg_gather_kernel(const unsigned short* __restrict__ xw,
                                                         const float* __restrict__ dinv,
                                                         const int* __restrict__ row_ptr,
                                                         const int* __restrict__ csr_src,
                                                         const float* __restrict__ b,
                                                         unsigned short* __restrict__ h,
                                                         const float* __restrict__ Wc,
                                                         const float* __restrict__ bc,
                                                         float* __restrict__ out, int n) {
    int v = (blockIdx.x * 256 + threadIdx.x) >> 6;
    if (v >= n) return;
    int lane = threadIdx.x & 63;

    int beg = __builtin_amdgcn_readfirstlane(row_ptr[v]);
    int end = __builtin_amdgcn_readfirstlane(row_ptr[v + 1]);

    const unsigned int* xw32 = (const unsigned int*)xw;   // 2 bf16 per word
    float a0 = 0.f, a1 = 0.f;                              // cols 2*lane, 2*lane+1

    int j = beg;
    for (; j + 4 <= end; j += 4) {
        int s0 = __builtin_amdgcn_readfirstlane(csr_src[j + 0]);
        int s1 = __builtin_amdgcn_readfirstlane(csr_src[j + 1]);
        int s2 = __builtin_amdgcn_readfirstlane(csr_src[j + 2]);
        int s3 = __builtin_amdgcn_readfirstlane(csr_src[j + 3]);
        float d0 = dinv[s0], d1 = dinv[s1], d2 = dinv[s2], d3 = dinv[s3];
        unsigned int w0 = xw32[(size_t)s0 * 64 + lane];
        unsigned int w1 = xw32[(size_t)s1 * 64 + lane];
        unsigned int w2 = xw32[(size_t)s2 * 64 + lane];
        unsigned int w3 = xw32[(size_t)s3 * 64 + lane];
        a0 = fmaf(d0, lof(w0), a0); a1 = fmaf(d0, hif(w0), a1);
        a0 = fmaf(d1, lof(w1), a0); a1 = fmaf(d1, hif(w1), a1);
        a0 = fmaf(d2, lof(w2), a0); a1 = fmaf(d2, hif(w2), a1);
        a0 = fmaf(d3, lof(w3), a0); a1 = fmaf(d3, hif(w3), a1);
    }
    for (; j < end; ++j) {
        int s0 = __builtin_amdgcn_readfirstlane(csr_src[j]);
        float d0 = dinv[s0];
        unsigned int w0 = xw32[(size_t)s0 * 64 + lane];
        a0 = fmaf(d0, lof(w0), a0); a1 = fmaf(d0, hif(w0), a1);
    }

    float dv = dinv[v];
    unsigned int wv = xw32[(size_t)v * 64 + lane];
    float2 bb = *reinterpret_cast<const float2*>(b + 2 * lane);
    float s2v = dv * dv;
    float r0 = fmaxf(dv * a0 + s2v * lof(wv) + bb.x, 0.f);
    float r1 = fmaxf(dv * a1 + s2v * hif(wv) + bb.y, 0.f);

    if (!CLS) {
        unsigned int o = (unsigned int)f2bf(r0) | ((unsigned int)f2bf(r1) << 16);
        *reinterpret_cast<unsigned int*>(h + (size_t)v * HID + 2 * lane) = o;
    } else {
        // Wc[c*2+0]=class0 weight for col c, Wc[c*2+1]=class1.
        float4 qw = *reinterpret_cast<const float4*>(Wc + 4 * lane);
        float p0 = r0 * qw.x + r1 * qw.z;
        float p1 = r0 * qw.y + r1 * qw.w;
#pragma unroll
        for (int off = 1; off < 64; off <<= 1) {
            p0 += __shfl_xor(p0, off);
            p1 += __shfl_xor(p1, off);
        }
        if (lane == 0) {
            float l0 = p0 + bc[0];
            float l1 = p1 + bc[1];
            float m = fmaxf(l0, l1);
            float lse = m + logf(expf(l0 - m) + expf(l1 - m));
            out[(size_t)v * 2 + 0] = l0 - lse;
            out[(size_t)v * 2 + 1] = l1 - lse;
        }
    }
}

// ---------------- launch ----------------

static inline size_t align256(size_t x) { return (x + 255) & ~(size_t)255; }

extern "C" void kernel_launch(void* const* d_in, const int* in_sizes, int n_in,
                              void* d_out, int out_size, void* d_ws, size_t ws_size,
                              hipStream_t stream) {
    const float* x   = (const float*)d_in[0];
    const int*   ei  = (const int*)d_in[1];     // int32 per harness contract
    const float* W1  = (const float*)d_in[2];
    const float* b1  = (const float*)d_in[3];
    const float* W2  = (const float*)d_in[4];
    const float* b2  = (const float*)d_in[5];
    const float* W3  = (const float*)d_in[6];
    const float* b3  = (const float*)d_in[7];
    const float* Wc  = (const float*)d_in[8];
    const float* bc  = (const float*)d_in[9];
    float*       out = (float*)d_out;

    const int* src = ei;             // edge_index[0,:]
    const int* dst = ei + N_EDGES;   // edge_index[1,:]

    // workspace layout (bcnt and gfill adjacent for one zero pass)
    size_t off = 0;
    size_t o_dinv    = off; off = align256(off + (size_t)N_NODES * 4);
    size_t o_rowptr  = off; off = align256(off + (size_t)(N_NODES + 1) * 4);
    size_t o_bcnt    = off;
    size_t o_gfill   = o_bcnt + (size_t)NB * 4;
                            off = align256(o_gfill + (size_t)NB * 4);
    size_t o_bbase   = off; off = align256(off + (size_t)(NB + 1) * 4);
    size_t o_csr     = off; off = align256(off + (size_t)N_EDGES * 4);
    size_t o_stg     = off; off = align256(off + (size_t)N_EDGES * 4);
    size_t o_blob1   = off; off = align256(off + (size_t)(F_IN / 32) * 8 * 64 * 8 * 2);
    size_t o_blob2   = off; off = align256(off + (size_t)(HID / 32) * 8 * 64 * 8 * 2);
    size_t o_blob3   = off; off = align256(off + (size_t)(HID / 32) * 8 * 64 * 8 * 2);
    size_t o_bufA    = off; off = align256(off + (size_t)N_NODES * HID * 2);
    size_t o_bufB    = off; off = align256(off + (size_t)N_NODES * HID * 2);
    size_t need = off;                           // ~65 MB

    const int nThr = 256;
    const int gOut = (out_size + nThr - 1) / nThr;
    if (ws_size < need) {
        zero_f_kernel<<<gOut, nThr, 0, stream>>>(out, out_size);
        return;
    }

    char* ws = (char*)d_ws;
    float*          dinv    = (float*)(ws + o_dinv);
    int*            row_ptr = (int*)(ws + o_rowptr);
    int*            bcnt    = (int*)(ws + o_bcnt);
    int*            gfill   = (int*)(ws + o_gfill);
    int*            bbase   = (int*)(ws + o_bbase);
    int*            csr_src = (int*)(ws + o_csr);
    unsigned int*   stg     = (unsigned int*)(ws + o_stg);
    unsigned short* blob1   = (unsigned short*)(ws + o_blob1);
    unsigned short* blob2   = (unsigned short*)(ws + o_blob2);
    unsigned short* blob3   = (unsigned short*)(ws + o_blob3);
    unsigned short* bufA    = (unsigned short*)(ws + o_bufA);   // xw (bf16)
    unsigned short* bufB    = (unsigned short*)(ws + o_bufB);   // h  (bf16)

    const int gW = (N_NODES * 64 + nThr - 1) / nThr;   // one wave per node
    const int gG = (N_NODES + 127) / 128;

    // ---- bucketed CSR build (5 kernels) ----
    zero_int_kernel<<<(2 * NB + 255) / 256, nThr, 0, stream>>>(bcnt, 2 * NB); // bcnt+gfill
    bucket_count_kernel<<<N_CHUNKS, nThr, 0, stream>>>(dst, bcnt, N_EDGES);
    scan_bucket_kernel<<<1, 512, 0, stream>>>(bcnt, bbase);
    stage_kernel<<<N_CHUNKS, nThr, 0, stream>>>(src, dst, bbase, gfill, stg, N_EDGES);
    bucket_finalize_kernel<<<NB, nThr, 0, stream>>>(stg, bbase, dinv, row_ptr, csr_src, N_NODES);

    // ---- W blobs ----
    prep_blob_kernel<F_IN><<<16, nThr, 0, stream>>>(W1, blob1);
    prep_blob_kernel<HID><<<8, nThr, 0, stream>>>(W2, blob2);
    prep_blob_kernel<HID><<<8, nThr, 0, stream>>>(W3, blob3);

    // ---- layers ----
    mfma_gemm_kernel<F_IN, false><<<gG, nThr, 0, stream>>>(x, blob1, bufA, N_NODES);
    agg_gather_kernel<false><<<gW, nThr, 0, stream>>>(bufA, dinv, row_ptr, csr_src, b1,
                                                      bufB, nullptr, nullptr, nullptr, N_NODES);

    mfma_gemm_kernel<HID, true><<<gG, nThr, 0, stream>>>(bufB, blob2, bufA, N_NODES);
    agg_gather_kernel<false><<<gW, nThr, 0, stream>>>(bufA, dinv, row_ptr, csr_src, b2,
                                                      bufB, nullptr, nullptr, nullptr, N_NODES);

    mfma_gemm_kernel<HID, true><<<gG, nThr, 0, stream>>>(bufB, blob3, bufA, N_NODES);
    // layer-3 aggregation with fused classifier + log_softmax
    agg_gather_kernel<true><<<gW, nThr, 0, stream>>>(bufA, dinv, row_ptr, csr_src, b3,
                                                     nullptr, Wc, bc, out, N_NODES);
}

// Round 9
// 319.199 us; speedup vs baseline: 3.1000x; 1.0546x over previous
//
#include <hip/hip_runtime.h>
#include <hip/hip_bf16.h>
#include <cstdint>
#include <cstddef>

#define N_NODES 100000
#define N_EDGES 1600000
#define F_IN    256
#define HID     128
#define NB       ((N_NODES + 255) >> 8)                        // 391 dst-buckets
#define F3_CHUNK 7168
#define N_CHUNKS ((N_EDGES + F3_CHUNK - 1) / F3_CHUNK)         // 224

typedef __attribute__((ext_vector_type(8))) short  bf16x8;
typedef __attribute__((ext_vector_type(4))) float  f32x4;

static __device__ inline float bf2f(unsigned short u) {
    return __uint_as_float(((unsigned int)u) << 16);
}
static __device__ inline unsigned short f2bf(float f) {
    union { __hip_bfloat16 h; unsigned short u; } c;
    c.h = __float2bfloat16(f);
    return c.u;
}
static __device__ inline float lof(unsigned int w) { return __uint_as_float(w << 16); }
static __device__ inline float hif(unsigned int w) { return __uint_as_float(w & 0xffff0000u); }

// ---------------- utility ----------------

__global__ __launch_bounds__(256) void zero_f_kernel(float* __restrict__ p, int n) {
    int i = blockIdx.x * 256 + threadIdx.x;
    if (i < n) p[i] = 0.f;
}

// ---------------- bucketed CSR build (consolidated) ----------------
// count: per-chunk LDS histogram -> ccnt[b][c] (transposed, plain stores)

__global__ __launch_bounds__(256) void count_kernel(const int* __restrict__ dst,
                                                    int* __restrict__ ccnt, int nE) {
    __shared__ int c[NB];
    for (int i = threadIdx.x; i < NB; i += 256) c[i] = 0;
    __syncthreads();
    int base = blockIdx.x * F3_CHUNK;
    int m = min(F3_CHUNK, nE - base);
    for (int t = threadIdx.x; t < m; t += 256)
        atomicAdd(&c[dst[base + t] >> 8], 1);
    __syncthreads();
    for (int i = threadIdx.x; i < NB; i += 256)
        ccnt[i * N_CHUNKS + blockIdx.x] = c[i];
}

// scanA: per-bucket exclusive scan over its 224 chunk counts (in place) + total

__global__ __launch_bounds__(256) void scanA_kernel(int* __restrict__ ccnt,
                                                    int* __restrict__ btot) {
    __shared__ int s[256];
    const int b = blockIdx.x;
    const int t = threadIdx.x;
    int v = (t < N_CHUNKS) ? ccnt[b * N_CHUNKS + t] : 0;
    s[t] = v;
    __syncthreads();
    for (int off = 1; off < 256; off <<= 1) {
        int add = (t >= off) ? s[t - off] : 0;
        __syncthreads();
        s[t] += add;
        __syncthreads();
    }
    if (t < N_CHUNKS) ccnt[b * N_CHUNKS + t] = s[t] - v;   // exclusive
    if (t == 255) btot[b] = s[255];                        // bucket total
}

// scanB: exclusive scan of 391 bucket totals -> bbase

__global__ __launch_bounds__(512) void scanB_kernel(const int* __restrict__ btot,
                                                    int* __restrict__ bbase) {
    __shared__ int s[512];
    int t = threadIdx.x;
    int v = (t < NB) ? btot[t] : 0;
    s[t] = v;
    __syncthreads();
    for (int off = 1; off < 512; off <<= 1) {
        int add = (t >= off) ? s[t - off] : 0;
        __syncthreads();
        s[t] += add;
        __syncthreads();
    }
    if (t < NB) bbase[t] = s[t] - v;
    if (t == 0) bbase[NB] = N_EDGES;
}

// stage (single pass): slot = bbase[b] + ccnt[b][chunk] + LDS-cnt++
// writes packed (src<<8)|(dst&255) grouped by dst-bucket

__global__ __launch_bounds__(256) void stage_kernel(const int* __restrict__ src,
                                                    const int* __restrict__ dst,
                                                    const int* __restrict__ ccnt,
                                                    const int* __restrict__ bbase,
                                                    unsigned int* __restrict__ stg, int nE) {
    __shared__ int cnt[NB];
    __shared__ int bas[NB];
    const int chunk = blockIdx.x;
    for (int i = threadIdx.x; i < NB; i += 256) {
        cnt[i] = 0;
        bas[i] = bbase[i] + ccnt[i * N_CHUNKS + chunk];
    }
    __syncthreads();
    int base = chunk * F3_CHUNK;
    int m = min(F3_CHUNK, nE - base);
    for (int t = threadIdx.x; t < m; t += 256) {
        int d = dst[base + t];
        int s = src[base + t];
        int bkt = d >> 8;
        int k = atomicAdd(&cnt[bkt], 1);
        stg[bas[bkt] + k] = ((unsigned int)s << 8) | (unsigned int)(d & 255);
    }
}

// fused finalize: per-bucket deg -> dinv, LDS scan -> row_ptr, fill -> csr_src

__global__ __launch_bounds__(256) void bucket_finalize_kernel(
        const unsigned int* __restrict__ stg,
        const int* __restrict__ bbase,
        float* __restrict__ dinv,
        int* __restrict__ row_ptr,
        int* __restrict__ csr_src, int n) {
    __shared__ int c[256];
    __shared__ int s[256];
    __shared__ int lofs[256];
    const int b = blockIdx.x;
    const int t = threadIdx.x;
    const int beg = bbase[b], end = bbase[b + 1];

    c[t] = 0;
    __syncthreads();
    for (int i = beg + t; i < end; i += 256)
        atomicAdd(&c[stg[i] & 255u], 1);
    __syncthreads();

    const int node = b * 256 + t;
    const int myDeg = c[t];
    if (node < n) dinv[node] = rsqrtf((float)myDeg + 1.0f);   // +1 self-loop

    s[t] = myDeg;
    __syncthreads();
    for (int off = 1; off < 256; off <<= 1) {
        int add = (t >= off) ? s[t - off] : 0;
        __syncthreads();
        s[t] += add;
        __syncthreads();
    }
    const int excl = s[t] - myDeg;
    lofs[t] = excl;
    if (node <= n) row_ptr[node] = beg + excl;

    __syncthreads();
    c[t] = 0;
    __syncthreads();
    for (int i = beg + t; i < end; i += 256) {
        unsigned int p = stg[i];
        int dl = (int)(p & 255u);
        int k = atomicAdd(&c[dl], 1);
        csr_src[beg + lofs[dl] + k] = (int)(p >> 8);
    }
}

// ---------------- W -> fragment blobs (all 3 layers, one launch) -----------
// blob entry tid = (s*8 + c)*64 + lane: W[k=s*32+(lane>>4)*8+j][col=c*16+(lane&15)]

static __device__ inline void blob_fill(const float* __restrict__ W,
                                        unsigned short* __restrict__ blob, int tid) {
    int lane = tid & 63;
    int c    = (tid >> 6) & 7;
    int s    = tid >> 9;
    int col  = c * 16 + (lane & 15);
    int kb   = s * 32 + (lane >> 4) * 8;
    bf16x8 o;
#pragma unroll
    for (int j = 0; j < 8; ++j)
        o[j] = (short)f2bf(W[(size_t)(kb + j) * HID + col]);
    *reinterpret_cast<bf16x8*>(blob + (size_t)tid * 8) = o;
}

// blocks 0..15 -> W1 (K=256, 4096 entries); 16..23 -> W2; 24..31 -> W3
__global__ __launch_bounds__(256) void prep_blob_all_kernel(const float* __restrict__ W1,
                                                            const float* __restrict__ W2,
                                                            const float* __restrict__ W3,
                                                            unsigned short* __restrict__ blob1,
                                                            unsigned short* __restrict__ blob2,
                                                            unsigned short* __restrict__ blob3) {
    int blk = blockIdx.x;
    if (blk < 16) {
        blob_fill(W1, blob1, blk * 256 + threadIdx.x);
    } else if (blk < 24) {
        blob_fill(W2, blob2, (blk - 16) * 256 + threadIdx.x);
    } else {
        blob_fill(W3, blob3, (blk - 24) * 256 + threadIdx.x);
    }
}

// ---------------- MFMA GEMM: Y_bf16[N,128] = X[N,K] @ W[K,128] --------------

template <int K, bool IN_BF16>
__global__ __launch_bounds__(256) void mfma_gemm_kernel(const void* __restrict__ Xv,
                                                        const unsigned short* __restrict__ blob,
                                                        unsigned short* __restrict__ Y, int n) {
    constexpr int KSTEPS = K / 32;
    const int lane = threadIdx.x & 63;
    const int wave = threadIdx.x >> 6;
    const int rowbase = blockIdx.x * 128 + wave * 32;

    const int r0 = min(rowbase +      (lane & 15), n - 1);
    const int r1 = min(rowbase + 16 + (lane & 15), n - 1);
    const int koff = (lane >> 4) * 8;

    f32x4 acc0[8], acc1[8];
#pragma unroll
    for (int c = 0; c < 8; ++c) { acc0[c] = (f32x4)0.f; acc1[c] = (f32x4)0.f; }

#pragma unroll
    for (int s = 0; s < KSTEPS; ++s) {
        bf16x8 bfr[8];
#pragma unroll
        for (int c = 0; c < 8; ++c)
            bfr[c] = *reinterpret_cast<const bf16x8*>(blob + ((size_t)((s * 8 + c) * 64 + lane)) * 8);

        bf16x8 a0, a1;
        if (IN_BF16) {
            const unsigned short* Xb = (const unsigned short*)Xv;
            a0 = *reinterpret_cast<const bf16x8*>(Xb + (size_t)r0 * K + s * 32 + koff);
            a1 = *reinterpret_cast<const bf16x8*>(Xb + (size_t)r1 * K + s * 32 + koff);
        } else {
            const float* Xf = (const float*)Xv;
            const float4* p0 = reinterpret_cast<const float4*>(Xf + (size_t)r0 * K + s * 32 + koff);
            const float4* p1 = reinterpret_cast<const float4*>(Xf + (size_t)r1 * K + s * 32 + koff);
            float4 q0 = p0[0], q1 = p0[1], q2 = p1[0], q3 = p1[1];
            a0[0] = (short)f2bf(q0.x); a0[1] = (short)f2bf(q0.y);
            a0[2] = (short)f2bf(q0.z); a0[3] = (short)f2bf(q0.w);
            a0[4] = (short)f2bf(q1.x); a0[5] = (short)f2bf(q1.y);
            a0[6] = (short)f2bf(q1.z); a0[7] = (short)f2bf(q1.w);
            a1[0] = (short)f2bf(q2.x); a1[1] = (short)f2bf(q2.y);
            a1[2] = (short)f2bf(q2.z); a1[3] = (short)f2bf(q2.w);
            a1[4] = (short)f2bf(q3.x); a1[5] = (short)f2bf(q3.y);
            a1[6] = (short)f2bf(q3.z); a1[7] = (short)f2bf(q3.w);
        }

#pragma unroll
        for (int c = 0; c < 8; ++c) {
            acc0[c] = __builtin_amdgcn_mfma_f32_16x16x32_bf16(a0, bfr[c], acc0[c], 0, 0, 0);
            acc1[c] = __builtin_amdgcn_mfma_f32_16x16x32_bf16(a1, bfr[c], acc1[c], 0, 0, 0);
        }
    }

    const int col  = lane & 15;
    const int rsub = (lane >> 4) * 4;
#pragma unroll
    for (int c = 0; c < 8; ++c) {
#pragma unroll
        for (int r = 0; r < 4; ++r) {
            int row0 = rowbase + rsub + r;
            int row1 = rowbase + 16 + rsub + r;
            if (row0 < n) Y[(size_t)row0 * HID + c * 16 + col] = f2bf(acc0[c][r]);
            if (row1 < n) Y[(size_t)row1 * HID + c * 16 + col] = f2bf(acc1[c][r]);
        }
    }
}

// ---------------- aggregation (gather, one wave per node, scalarized) -------
// h[v] = relu( dinv[v]*sum_s dinv[s]*xw[s] + dinv[v]^2*xw[v] + b )
// Plain loads (uniform addrs -> SALU s_loads). CLS fuses classifier+logsoftmax.

template <bool CLS>
__global__ __launch_bounds__(256) void agg_gather_kernel(const unsigned short* __restrict__ xw,
                                                         const float* __restrict__ dinv,
                                                         const int* __restrict__ row_ptr,
                                                         const int* __restrict__ csr_src,
                                                         const float* __restrict__ b,
                                                         unsigned short* __restrict__ h,
                                                         const float* __restrict__ Wc,
                                                         const float* __restrict__ bc,
                                                         float* __restrict__ out, int n) {
    int v = (blockIdx.x * 256 + threadIdx.x) >> 6;
    if (v >= n) return;
    int lane = threadIdx.x & 63;

    int beg = __builtin_amdgcn_readfirstlane(row_ptr[v]);
    int end = __builtin_amdgcn_readfirstlane(row_ptr[v + 1]);

    const unsigned int* xw32 = (const unsigned int*)xw;   // 2 bf16 per word
    float a0 = 0.f, a1 = 0.f;                              // cols 2*lane, 2*lane+1

    int j = beg;
    for (; j + 4 <= end; j += 4) {
        int s0 = __builtin_amdgcn_readfirstlane(csr_src[j + 0]);
        int s1 = __builtin_amdgcn_readfirstlane(csr_src[j + 1]);
        int s2 = __builtin_amdgcn_readfirstlane(csr_src[j + 2]);
        int s3 = __builtin_amdgcn_readfirstlane(csr_src[j + 3]);
        float d0 = dinv[s0], d1 = dinv[s1], d2 = dinv[s2], d3 = dinv[s3];
        unsigned int w0 = xw32[(size_t)s0 * 64 + lane];
        unsigned int w1 = xw32[(size_t)s1 * 64 + lane];
        unsigned int w2 = xw32[(size_t)s2 * 64 + lane];
        unsigned int w3 = xw32[(size_t)s3 * 64 + lane];
        a0 = fmaf(d0, lof(w0), a0); a1 = fmaf(d0, hif(w0), a1);
        a0 = fmaf(d1, lof(w1), a0); a1 = fmaf(d1, hif(w1), a1);
        a0 = fmaf(d2, lof(w2), a0); a1 = fmaf(d2, hif(w2), a1);
        a0 = fmaf(d3, lof(w3), a0); a1 = fmaf(d3, hif(w3), a1);
    }
    for (; j < end; ++j) {
        int s0 = __builtin_amdgcn_readfirstlane(csr_src[j]);
        float d0 = dinv[s0];
        unsigned int w0 = xw32[(size_t)s0 * 64 + lane];
        a0 = fmaf(d0, lof(w0), a0); a1 = fmaf(d0, hif(w0), a1);
    }

    float dv = dinv[v];
    unsigned int wv = xw32[(size_t)v * 64 + lane];
    float2 bb = *reinterpret_cast<const float2*>(b + 2 * lane);
    float s2v = dv * dv;
    float r0 = fmaxf(dv * a0 + s2v * lof(wv) + bb.x, 0.f);
    float r1 = fmaxf(dv * a1 + s2v * hif(wv) + bb.y, 0.f);

    if (!CLS) {
        unsigned int o = (unsigned int)f2bf(r0) | ((unsigned int)f2bf(r1) << 16);
        *reinterpret_cast<unsigned int*>(h + (size_t)v * HID + 2 * lane) = o;
    } else {
        float4 qw = *reinterpret_cast<const float4*>(Wc + 4 * lane);
        float p0 = r0 * qw.x + r1 * qw.z;
        float p1 = r0 * qw.y + r1 * qw.w;
#pragma unroll
        for (int off = 1; off < 64; off <<= 1) {
            p0 += __shfl_xor(p0, off);
            p1 += __shfl_xor(p1, off);
        }
        if (lane == 0) {
            float l0 = p0 + bc[0];
            float l1 = p1 + bc[1];
            float m = fmaxf(l0, l1);
            float lse = m + logf(expf(l0 - m) + expf(l1 - m));
            out[(size_t)v * 2 + 0] = l0 - lse;
            out[(size_t)v * 2 + 1] = l1 - lse;
        }
    }
}

// ---------------- launch ----------------

static inline size_t align256(size_t x) { return (x + 255) & ~(size_t)255; }

extern "C" void kernel_launch(void* const* d_in, const int* in_sizes, int n_in,
                              void* d_out, int out_size, void* d_ws, size_t ws_size,
                              hipStream_t stream) {
    const float* x   = (const float*)d_in[0];
    const int*   ei  = (const int*)d_in[1];     // int32 per harness contract
    const float* W1  = (const float*)d_in[2];
    const float* b1  = (const float*)d_in[3];
    const float* W2  = (const float*)d_in[4];
    const float* b2  = (const float*)d_in[5];
    const float* W3  = (const float*)d_in[6];
    const float* b3  = (const float*)d_in[7];
    const float* Wc  = (const float*)d_in[8];
    const float* bc  = (const float*)d_in[9];
    float*       out = (float*)d_out;

    const int* src = ei;             // edge_index[0,:]
    const int* dst = ei + N_EDGES;   // edge_index[1,:]

    // workspace layout
    size_t off = 0;
    size_t o_dinv    = off; off = align256(off + (size_t)N_NODES * 4);
    size_t o_rowptr  = off; off = align256(off + (size_t)(N_NODES + 1) * 4);
    size_t o_ccnt    = off; off = align256(off + (size_t)NB * N_CHUNKS * 4);   // 350 KB
    size_t o_btot    = off; off = align256(off + (size_t)NB * 4);
    size_t o_bbase   = off; off = align256(off + (size_t)(NB + 1) * 4);
    size_t o_csr     = off; off = align256(off + (size_t)N_EDGES * 4);
    size_t o_stg     = off; off = align256(off + (size_t)N_EDGES * 4);
    size_t o_blob1   = off; off = align256(off + (size_t)(F_IN / 32) * 8 * 64 * 8 * 2);
    size_t o_blob2   = off; off = align256(off + (size_t)(HID / 32) * 8 * 64 * 8 * 2);
    size_t o_blob3   = off; off = align256(off + (size_t)(HID / 32) * 8 * 64 * 8 * 2);
    size_t o_bufA    = off; off = align256(off + (size_t)N_NODES * HID * 2);
    size_t o_bufB    = off; off = align256(off + (size_t)N_NODES * HID * 2);
    size_t need = off;                           // ~65.5 MB

    const int nThr = 256;
    const int gOut = (out_size + nThr - 1) / nThr;
    if (ws_size < need) {
        zero_f_kernel<<<gOut, nThr, 0, stream>>>(out, out_size);
        return;
    }

    char* ws = (char*)d_ws;
    float*          dinv    = (float*)(ws + o_dinv);
    int*            row_ptr = (int*)(ws + o_rowptr);
    int*            ccnt    = (int*)(ws + o_ccnt);
    int*            btot    = (int*)(ws + o_btot);
    int*            bbase   = (int*)(ws + o_bbase);
    int*            csr_src = (int*)(ws + o_csr);
    unsigned int*   stg     = (unsigned int*)(ws + o_stg);
    unsigned short* blob1   = (unsigned short*)(ws + o_blob1);
    unsigned short* blob2   = (unsigned short*)(ws + o_blob2);
    unsigned short* blob3   = (unsigned short*)(ws + o_blob3);
    unsigned short* bufA    = (unsigned short*)(ws + o_bufA);   // xw (bf16)
    unsigned short* bufB    = (unsigned short*)(ws + o_bufB);   // h  (bf16)

    const int gW = (N_NODES * 64 + nThr - 1) / nThr;   // one wave per node
    const int gG = (N_NODES + 127) / 128;

    // ---- CSR build (5 launches, no zeroing, single-pass stage) ----
    count_kernel<<<N_CHUNKS, nThr, 0, stream>>>(dst, ccnt, N_EDGES);
    scanA_kernel<<<NB, nThr, 0, stream>>>(ccnt, btot);
    scanB_kernel<<<1, 512, 0, stream>>>(btot, bbase);
    stage_kernel<<<N_CHUNKS, nThr, 0, stream>>>(src, dst, ccnt, bbase, stg, N_EDGES);
    bucket_finalize_kernel<<<NB, nThr, 0, stream>>>(stg, bbase, dinv, row_ptr, csr_src, N_NODES);

    // ---- W blobs (one launch) ----
    prep_blob_all_kernel<<<32, nThr, 0, stream>>>(W1, W2, W3, blob1, blob2, blob3);

    // ---- layers ----
    mfma_gemm_kernel<F_IN, false><<<gG, nThr, 0, stream>>>(x, blob1, bufA, N_NODES);
    agg_gather_kernel<false><<<gW, nThr, 0, stream>>>(bufA, dinv, row_ptr, csr_src, b1,
                                                      bufB, nullptr, nullptr, nullptr, N_NODES);

    mfma_gemm_kernel<HID, true><<<gG, nThr, 0, stream>>>(bufB, blob2, bufA, N_NODES);
    agg_gather_kernel<false><<<gW, nThr, 0, stream>>>(bufA, dinv, row_ptr, csr_src, b2,
                                                      bufB, nullptr, nullptr, nullptr, N_NODES);

    mfma_gemm_kernel<HID, true><<<gG, nThr, 0, stream>>>(bufB, blob3, bufA, N_NODES);
    agg_gather_kernel<true><<<gW, nThr, 0, stream>>>(bufA, dinv, row_ptr, csr_src, b3,
                                                     nullptr, Wc, bc, out, N_NODES);
}